// Round 2
// baseline (284.884 us; speedup 1.0000x reference)
//
#include <hip/hip_runtime.h>

// ---- problem constants ----
#define BB 32
#define CC 16
#define HH_ 128
#define WW_ 128

// ---- ws float layout (element offsets) ----
#define OFF_WX   0        // [i][o][9]   2304
#define OFF_WY   2304     // [i][o][9]   2304
#define OFF_W1   4608     // [j][c]      6144
#define OFF_W2T  10752    // [j][o]      2048
#define OFF_BX   12800    // 16
#define OFF_BY   12816    // 16
#define OFF_B1   12832    // 128
#define OFF_B2   12960    // 16
#define WS_FLOATS 12976

__global__ void prep_weights(const float* __restrict__ Wx, const float* __restrict__ bx,
                             const float* __restrict__ Wy, const float* __restrict__ by,
                             const float* __restrict__ W1, const float* __restrict__ b1,
                             const float* __restrict__ W2, const float* __restrict__ b2,
                             float* __restrict__ ws) {
    int t = blockIdx.x * blockDim.x + threadIdx.x;
    int stride = gridDim.x * blockDim.x;
    // conv weights: source [o][i][3][3] -> dest [i][o][9]
    for (int f = t; f < 2304; f += stride) {
        int k = f % 9;
        int rest = f / 9;
        int o = rest % 16;
        int i = rest / 16;
        int src = (o * 16 + i) * 9 + k;
        ws[OFF_WX + f] = Wx[src];
        ws[OFF_WY + f] = Wy[src];
    }
    // W1: [128][48] straight copy
    for (int f = t; f < 6144; f += stride) ws[OFF_W1 + f] = W1[f];
    // W2: [16][128] -> transposed [128][16]
    for (int f = t; f < 2048; f += stride) {
        int o = f % 16;
        int j = f / 16;
        ws[OFF_W2T + f] = W2[o * 128 + j];
    }
    for (int f = t; f < 128; f += stride) ws[OFF_B1 + f] = b1[f];
    if (t < 16) {
        ws[OFF_BX + t] = bx[t];
        ws[OFF_BY + t] = by[t];
        ws[OFF_B2 + t] = b2[t];
    }
}

// One block = one 16x16 pixel tile of one image.
// Thread t: hh = t & 15 (local h), ww = t >> 4 (local w) -> consecutive lanes
// have consecutive h, the contiguous-ish axis of out[b][w][h][16].
__global__ __launch_bounds__(256, 2) void nca_main(const float* __restrict__ x,
                                                   const float* __restrict__ ws,
                                                   float* __restrict__ out) {
    __shared__ float xs[16 * 18 * 18];  // [c][h(18)][w(18)] tile with halo

    const int tid = threadIdx.x;
    const int blk = blockIdx.x;
    const int b = blk >> 6;          // 64 tiles per image
    const int rem = blk & 63;
    const int wt = rem >> 3;
    const int ht = rem & 7;
    const int h0 = ht * 16;
    const int w0 = wt * 16;

    // ---- stage x tile (with zero-padded halo) into LDS ----
    const float* xb = x + (size_t)b * CC * HH_ * WW_;
    for (int f = tid; f < 16 * 18 * 18; f += 256) {
        int c = f / 324;
        int r2 = f - c * 324;
        int r = r2 / 18;
        int cc = r2 - r * 18;
        int gh = h0 - 1 + r;
        int gw = w0 - 1 + cc;
        float v = 0.0f;
        if ((unsigned)gh < 128u && (unsigned)gw < 128u)
            v = xb[(c * 128 + gh) * 128 + gw];
        xs[f] = v;
    }
    __syncthreads();

    const int hh = tid & 15;
    const int ww = tid >> 4;

    // ---- feat[48] = [convx(16), convy(16), x(16)] ----
    float feat[48];
#pragma unroll
    for (int c = 0; c < 16; ++c)
        feat[32 + c] = xs[c * 324 + (hh + 1) * 18 + (ww + 1)];
#pragma unroll
    for (int o = 0; o < 16; ++o) {
        feat[o] = ws[OFF_BX + o];
        feat[16 + o] = ws[OFF_BY + o];
    }

    for (int i = 0; i < 16; ++i) {
        float p[9];
#pragma unroll
        for (int kh = 0; kh < 3; ++kh)
#pragma unroll
            for (int kw = 0; kw < 3; ++kw)
                p[kh * 3 + kw] = xs[i * 324 + (hh + kh) * 18 + (ww + kw)];
        const float* wxp = ws + OFF_WX + i * 144;  // uniform addresses -> s_load
        const float* wyp = ws + OFF_WY + i * 144;
#pragma unroll
        for (int o = 0; o < 16; ++o) {
            float ax = feat[o];
            float ay = feat[16 + o];
#pragma unroll
            for (int k = 0; k < 9; ++k) {
                ax = fmaf(wxp[o * 9 + k], p[k], ax);
                ay = fmaf(wyp[o * 9 + k], p[k], ay);
            }
            feat[o] = ax;
            feat[16 + o] = ay;
        }
    }

    // ---- MLP: h = relu(W1 @ feat + b1) (128); out = W2 @ h + b2 (16) ----
    float acc[16];
#pragma unroll
    for (int o = 0; o < 16; ++o) acc[o] = ws[OFF_B2 + o];

#pragma unroll 2
    for (int j = 0; j < 128; ++j) {
        const float* w1p = ws + OFF_W1 + j * 48;  // uniform -> s_load
        float s0 = 0.f, s1 = 0.f, s2 = 0.f, s3 = 0.f;
#pragma unroll
        for (int c = 0; c < 48; c += 4) {
            s0 = fmaf(w1p[c + 0], feat[c + 0], s0);
            s1 = fmaf(w1p[c + 1], feat[c + 1], s1);
            s2 = fmaf(w1p[c + 2], feat[c + 2], s2);
            s3 = fmaf(w1p[c + 3], feat[c + 3], s3);
        }
        float hj = ws[OFF_B1 + j] + ((s0 + s1) + (s2 + s3));
        hj = fmaxf(hj, 0.0f);
        const float* w2p = ws + OFF_W2T + j * 16;  // uniform -> s_load (contiguous 16 dwords)
#pragma unroll
        for (int o = 0; o < 16; ++o) acc[o] = fmaf(w2p[o], hj, acc[o]);
    }

    // ---- store out[b][w0+ww][h0+hh][0..15] fp32 (64 B contiguous per thread) ----
    size_t ofs = (((size_t)b * 128 + (w0 + ww)) * 128 + (h0 + hh)) * 16;
    float4* op = reinterpret_cast<float4*>(out + ofs);
    op[0] = make_float4(acc[0],  acc[1],  acc[2],  acc[3]);
    op[1] = make_float4(acc[4],  acc[5],  acc[6],  acc[7]);
    op[2] = make_float4(acc[8],  acc[9],  acc[10], acc[11]);
    op[3] = make_float4(acc[12], acc[13], acc[14], acc[15]);
}

extern "C" void kernel_launch(void* const* d_in, const int* in_sizes, int n_in,
                              void* d_out, int out_size, void* d_ws, size_t ws_size,
                              hipStream_t stream) {
    const float* x  = (const float*)d_in[0];
    const float* Wx = (const float*)d_in[1];
    const float* bx = (const float*)d_in[2];
    const float* Wy = (const float*)d_in[3];
    const float* by = (const float*)d_in[4];
    const float* W1 = (const float*)d_in[5];
    const float* b1 = (const float*)d_in[6];
    const float* W2 = (const float*)d_in[7];
    const float* b2 = (const float*)d_in[8];
    float* ws = (float*)d_ws;
    float* out = (float*)d_out;

    hipLaunchKernelGGL(prep_weights, dim3(32), dim3(256), 0, stream,
                       Wx, bx, Wy, by, W1, b1, W2, b2, ws);
    hipLaunchKernelGGL(nca_main, dim3(2048), dim3(256), 0, stream, x, ws, out);
}

// Round 3
// 149.634 us; speedup vs baseline: 1.9039x; 1.9039x over previous
//
#include <hip/hip_runtime.h>
#include <hip/hip_bf16.h>

typedef __hip_bfloat16 bf16;
typedef __attribute__((ext_vector_type(8))) short short8;   // bf16x8 MFMA frag (4 VGPR)
typedef __attribute__((ext_vector_type(4))) short short4v;  // bf16x4 (8 B)
typedef __attribute__((ext_vector_type(4))) float float4v;  // MFMA acc frag

// ---- geometry ----
#define TH 16          // tile height (pixels), = MFMA N per n-tile
#define TW 8           // tile width  -> 128 pixels per block
#define HALO_H 18
#define HALO_W 10
#define CS 24          // xs channel stride (16 used): lane stride 48B = 12 dw -> 2-way banks, 16B aligned
#define KS 136         // hs k stride (128 used): row stride 272B -> 2-way banks, 16B aligned

// ---- ws layout ----
// bf16 region (offset 0):   W1E [128][160]  (20480 el)
//                           W2B [16][128]   (2048 el)   at el offset 20480
// float region (byte 45056): b1e[128], b2[16]
#define W2B_EL 20480
#define WSF_BYTE 45056

__global__ void prep(const float* __restrict__ Wx, const float* __restrict__ bx,
                     const float* __restrict__ Wy, const float* __restrict__ by,
                     const float* __restrict__ W1, const float* __restrict__ b1,
                     const float* __restrict__ W2, const float* __restrict__ b2,
                     bf16* __restrict__ wsb, float* __restrict__ wsf) {
    int t = blockIdx.x * blockDim.x + threadIdx.x;
    int stride = gridDim.x * blockDim.x;
    // W1_eff[j][k], k = g*16 + c, g = kh*3+kw (g==9 zero pad), K padded to 160
    for (int f = t; f < 128 * 160; f += stride) {
        int j = f / 160, k = f - j * 160;
        int g = k >> 4, c = k & 15;
        float v = 0.0f;
        if (g < 9) {
            for (int o = 0; o < 16; ++o) {
                float wx = Wx[(o * 16 + c) * 9 + g];
                float wy = Wy[(o * 16 + c) * 9 + g];
                v = fmaf(W1[j * 48 + o], wx, v);
                v = fmaf(W1[j * 48 + 16 + o], wy, v);
            }
            if (g == 4) v += W1[j * 48 + 32 + c];  // identity (concat-x) center tap
        }
        wsb[f] = __float2bfloat16(v);
    }
    // W2 [16][128] -> bf16
    for (int f = t; f < 2048; f += stride) wsb[W2B_EL + f] = __float2bfloat16(W2[f]);
    // b1_eff
    for (int j = t; j < 128; j += stride) {
        float v = b1[j];
        for (int o = 0; o < 16; ++o) {
            v = fmaf(W1[j * 48 + o], bx[o], v);
            v = fmaf(W1[j * 48 + 16 + o], by[o], v);
        }
        wsf[j] = v;
    }
    if (t < 16) wsf[128 + t] = b2[t];
}

// Fused: h[128][px] = relu(W1e @ im2col(x) + b1e);  out[16][px] = W2 @ h + b2
// Block: 16h x 8w pixel tile. 4 waves, 2x2 (m x n): wave = 64m x 64n.
__global__ __launch_bounds__(256, 2) void nca_mfma(const float* __restrict__ x,
                                                   const bf16* __restrict__ wsb,
                                                   const float* __restrict__ wsf,
                                                   float* __restrict__ out,
                                                   int gridTiles) {
    __shared__ bf16 xs[HALO_W * HALO_H * CS];  // [ww][hh][c]
    __shared__ bf16 hs[128 * KS];              // [pixel][k(m)]

    const int tid = threadIdx.x;
    const int wave = tid >> 6;
    const int lane = tid & 63;
    const int hl = lane & 15;       // MFMA col = pixel local h
    const int quad = lane >> 4;
    const int r0 = quad * 4;        // C/D row base
    const int mgrp = wave >> 1;     // m 0..63 / 64..127
    const int ngrp = wave & 1;      // n-tiles ngrp*4..+3

    // ---- one-time: A fragments (W1e) into registers ----
    // A[m = lane&15][k = quad*8+j]; k = q*32 + quad*8
    short8 afrag[4][5];
#pragma unroll
    for (int mt = 0; mt < 4; ++mt) {
        int m = mgrp * 64 + mt * 16 + hl;
#pragma unroll
        for (int q = 0; q < 5; ++q)
            afrag[mt][q] = *(const short8*)(wsb + m * 160 + q * 32 + quad * 8);
    }
    short8 w2frag[4];
#pragma unroll
    for (int r = 0; r < 4; ++r)
        w2frag[r] = *(const short8*)(wsb + W2B_EL + hl * 128 + r * 32 + quad * 8);
    float b1r[4][4];
#pragma unroll
    for (int mt = 0; mt < 4; ++mt)
#pragma unroll
        for (int r = 0; r < 4; ++r) b1r[mt][r] = wsf[mgrp * 64 + mt * 16 + r0 + r];
    float b2r[4];
#pragma unroll
    for (int r = 0; r < 4; ++r) b2r[r] = wsf[128 + r0 + r];

    // ---- grid-stride over 4096 tiles (32 img x 8 ht x 16 wt) ----
    for (int t = blockIdx.x; t < 4096; t += gridTiles) {
        int b = t >> 7;
        int rem = t & 127;
        int wt = rem >> 3, ht = rem & 7;
        int h0 = ht * 16, w0 = wt * 8;

        __syncthreads();  // protect xs/hs from previous iteration's readers

        // ---- stage x tile -> LDS bf16 [ww][hh][c] ----
        const float* xb = x + (size_t)b * 16 * 128 * 128;
        for (int f = tid; f < 16 * HALO_H * HALO_W; f += 256) {
            int c = f / (HALO_H * HALO_W);
            int rr = f - c * (HALO_H * HALO_W);
            int hh = rr / HALO_W;
            int ww = rr - hh * HALO_W;
            int gh = h0 - 1 + hh, gw = w0 - 1 + ww;
            float v = 0.0f;
            if ((unsigned)gh < 128u && (unsigned)gw < 128u)
                v = xb[(c * 128 + gh) * 128 + gw];
            xs[(ww * HALO_H + hh) * CS + c] = __float2bfloat16(v);
        }
        __syncthreads();

        // ---- GEMM1: acc[mt][nt] = W1e @ patches ----
        float4v acc[4][4];
#pragma unroll
        for (int mt = 0; mt < 4; ++mt)
#pragma unroll
            for (int nt = 0; nt < 4; ++nt) acc[mt][nt] = (float4v)0.0f;

#pragma unroll
        for (int q = 0; q < 5; ++q) {
            int g = q * 2 + (quad >> 1);
            if (g > 8) g = 8;            // K-pad: read valid data, A is zero there
            int kh = g / 3, kw = g - kh * 3;
            int c0 = (quad & 1) * 8;
            short8 bfrag[4];
#pragma unroll
            for (int nt = 0; nt < 4; ++nt) {
                int ww = ngrp * 4 + nt + kw;
                bfrag[nt] = *(const short8*)(xs + (ww * HALO_H + hl + kh) * CS + c0);
            }
#pragma unroll
            for (int nt = 0; nt < 4; ++nt)
#pragma unroll
                for (int mt = 0; mt < 4; ++mt)
                    acc[mt][nt] = __builtin_amdgcn_mfma_f32_16x16x32_bf16(
                        afrag[mt][q], bfrag[nt], acc[mt][nt], 0, 0, 0);
        }

        // ---- epilogue 1: bias + relu -> hs[pixel][m] bf16 ----
#pragma unroll
        for (int mt = 0; mt < 4; ++mt)
#pragma unroll
            for (int nt = 0; nt < 4; ++nt) {
                int p = (ngrp * 4 + nt) * 16 + hl;
                int m = mgrp * 64 + mt * 16 + r0;
                short4v pk;
#pragma unroll
                for (int r = 0; r < 4; ++r) {
                    float v = acc[mt][nt][r] + b1r[mt][r];
                    v = fmaxf(v, 0.0f);
                    bf16 hb = __float2bfloat16(v);
                    pk[r] = *reinterpret_cast<short*>(&hb);
                }
                *(short4v*)(hs + p * KS + m) = pk;
            }
        __syncthreads();

        // ---- GEMM2: out16 = W2 @ h ; each wave: n-tiles 2w, 2w+1 ----
        float4v acc2[2];
        acc2[0] = (float4v)0.0f;
        acc2[1] = (float4v)0.0f;
#pragma unroll
        for (int r = 0; r < 4; ++r) {
#pragma unroll
            for (int i = 0; i < 2; ++i) {
                int p = (wave * 2 + i) * 16 + hl;
                short8 bfrag = *(const short8*)(hs + p * KS + r * 32 + quad * 8);
                acc2[i] = __builtin_amdgcn_mfma_f32_16x16x32_bf16(
                    w2frag[r], bfrag, acc2[i], 0, 0, 0);
            }
        }

        // ---- store out[b][w0+nt][h0+hl][r0..r0+3] fp32, fully coalesced ----
#pragma unroll
        for (int i = 0; i < 2; ++i) {
            int nt = wave * 2 + i;
            size_t ofs = (((size_t)b * 128 + (w0 + nt)) * 128 + (h0 + hl)) * 16 + r0;
            float4 v = make_float4(acc2[i][0] + b2r[0], acc2[i][1] + b2r[1],
                                   acc2[i][2] + b2r[2], acc2[i][3] + b2r[3]);
            *(float4*)(out + ofs) = v;
        }
    }
}

extern "C" void kernel_launch(void* const* d_in, const int* in_sizes, int n_in,
                              void* d_out, int out_size, void* d_ws, size_t ws_size,
                              hipStream_t stream) {
    const float* x  = (const float*)d_in[0];
    const float* Wx = (const float*)d_in[1];
    const float* bx = (const float*)d_in[2];
    const float* Wy = (const float*)d_in[3];
    const float* by = (const float*)d_in[4];
    const float* W1 = (const float*)d_in[5];
    const float* b1 = (const float*)d_in[6];
    const float* W2 = (const float*)d_in[7];
    const float* b2 = (const float*)d_in[8];
    bf16* wsb = (bf16*)d_ws;
    float* wsf = (float*)((char*)d_ws + WSF_BYTE);
    float* out = (float*)d_out;

    hipLaunchKernelGGL(prep, dim3(80), dim3(256), 0, stream,
                       Wx, bx, Wy, by, W1, b1, W2, b2, wsb, wsf);
    const int grid = 1024;  // 4 tiles/block grid-stride: amortizes A-register load
    hipLaunchKernelGGL(nca_mfma, dim3(grid), dim3(256), 0, stream,
                       x, wsb, wsf, out, grid);
}